// Round 2
// baseline (17499.397 us; speedup 1.0000x reference)
//
#include <hip/hip_runtime.h>
#include <hip/hip_bf16.h>
#include <hip/hip_fp16.h>

// ---------------------------------------------------------------------------
// ModelInstructionAggregate: token-LSTM (batch 8192, T<=16) -> sequential
// instruction-LSTM (8192 steps, batch 1) -> Linear(256->1).
// Pipeline: transpose weights -> fused token LSTM (fp32) -> XI GEMM (fp32) ->
// single-CU sequential LSTM (f16 weights in regs+LDS, fp32 accum) -> GEMV.
// Round 2 fix: output dtype is float32 (harness: "bfloat16 -> __hip_bfloat16*,
// else float*"; reference returns float32). Round 1 wrote bf16 -> packed-pair
// garbage in the first half of d_out and zeros in the second half.
// ---------------------------------------------------------------------------

constexpr int H_ = 256;    // hidden
constexpr int T_ = 16;     // max token steps
constexpr int N_ = 8192;   // instructions
constexpr int BI = 16;     // instructions per block in batched kernels

typedef _Float16 half_t;
typedef half_t half2_t __attribute__((ext_vector_type(2)));

#if __has_builtin(__builtin_amdgcn_fdot2)
#define FDOT2(w, h, acc) __builtin_amdgcn_fdot2((w), (h), (acc), false)
#else
__device__ __forceinline__ float fdot2_emul(half2_t w, half2_t h, float acc) {
    return acc + (float)w.x * (float)h.x + (float)w.y * (float)h.y;
}
#define FDOT2(w, h, acc) fdot2_emul((w), (h), (acc))
#endif

__device__ __forceinline__ float sigmoidf_(float x) {
    return 1.0f / (1.0f + __expf(-x));
}
__device__ __forceinline__ float tanhf_(float x) {
    // 2*sigmoid(2x)-1 ; saturates correctly for |x| large (no NaN)
    return 2.0f / (1.0f + __expf(-2.0f * x)) - 1.0f;
}

// --------------------------- weight transposes -----------------------------
// Wt[kb][row] (float4), kb in [0,128): kb<64 -> Wih[row][4kb..], else Whh.
__global__ __launch_bounds__(256) void k_transpose_cat(
    const float* __restrict__ Wih, const float* __restrict__ Whh,
    float4* __restrict__ Wt)
{
    int tid = blockIdx.x * 256 + threadIdx.x;      // 1024 rows * 128 kb
    int kb = tid & 127, row = tid >> 7;
    float4 v = (kb < 64) ? ((const float4*)Wih)[row * 64 + kb]
                         : ((const float4*)Whh)[row * 64 + (kb - 64)];
    Wt[kb * 1024 + row] = v;
}

__global__ __launch_bounds__(256) void k_transpose_i(
    const float* __restrict__ Wsrc, float4* __restrict__ Wt)
{
    int tid = blockIdx.x * 256 + threadIdx.x;      // 1024 rows * 64 kb
    int kb = tid & 63, row = tid >> 6;
    Wt[kb * 1024 + row] = ((const float4*)Wsrc)[row * 64 + kb];
}

// ----------------------- phase 1: batched token LSTM -----------------------
// One block = 16 instructions; thread j owns hidden unit j (gate rows j,
// 256+j, 512+j, 768+j). Weights read coalesced from transposed layout.
__global__ __launch_bounds__(256, 4) void k_token_lstm(
    const float* __restrict__ tokens, const int* __restrict__ lengths,
    const float4* __restrict__ Wt,   // [128][1024] float4 (x-part then h-part)
    const float* __restrict__ bih, const float* __restrict__ bhh,
    float* __restrict__ embeds)      // [N_][H_]
{
    __shared__ __align__(16) float xs[BI][H_];
    __shared__ __align__(16) float hs[BI][H_];
    __shared__ __align__(16) float cs[BI][H_];
    __shared__ int len[BI];

    const int j = threadIdx.x;
    const int n0 = blockIdx.x * BI;
    if (j < BI) len[j] = lengths[n0 + j];
#pragma unroll
    for (int i = 0; i < BI; ++i) { hs[i][j] = 0.f; cs[i][j] = 0.f; }
    const float b0 = bih[j]       + bhh[j];
    const float b1 = bih[256 + j] + bhh[256 + j];
    const float b2 = bih[512 + j] + bhh[512 + j];
    const float b3 = bih[768 + j] + bhh[768 + j];
    __syncthreads();

    for (int t = 0; t < T_; ++t) {
        // stage x_t for the block's 16 instructions (coalesced float4)
#pragma unroll
        for (int q = 0; q < 4; ++q) {
            int idx = j + q * 256;
            int i = idx >> 6, e4 = idx & 63;
            ((float4*)xs)[i * 64 + e4] =
                ((const float4*)tokens)[((size_t)(n0 + i) * T_ + t) * 64 + e4];
        }
        __syncthreads();

        float a0[BI], a1[BI], a2[BI], a3[BI];
#pragma unroll
        for (int i = 0; i < BI; ++i) { a0[i] = 0.f; a1[i] = 0.f; a2[i] = 0.f; a3[i] = 0.f; }

        // x part (k = 0..255)
        for (int kb = 0; kb < 64; ++kb) {
            float4 w0 = Wt[kb * 1024 + j];
            float4 w1 = Wt[kb * 1024 + 256 + j];
            float4 w2 = Wt[kb * 1024 + 512 + j];
            float4 w3 = Wt[kb * 1024 + 768 + j];
#pragma unroll
            for (int i = 0; i < BI; ++i) {
                float4 x4 = ((const float4*)xs)[i * 64 + kb];
                a0[i] += w0.x * x4.x + w0.y * x4.y + w0.z * x4.z + w0.w * x4.w;
                a1[i] += w1.x * x4.x + w1.y * x4.y + w1.z * x4.z + w1.w * x4.w;
                a2[i] += w2.x * x4.x + w2.y * x4.y + w2.z * x4.z + w2.w * x4.w;
                a3[i] += w3.x * x4.x + w3.y * x4.y + w3.z * x4.z + w3.w * x4.w;
            }
        }
        // h part (k = 256..511)
        for (int kb = 0; kb < 64; ++kb) {
            float4 w0 = Wt[(64 + kb) * 1024 + j];
            float4 w1 = Wt[(64 + kb) * 1024 + 256 + j];
            float4 w2 = Wt[(64 + kb) * 1024 + 512 + j];
            float4 w3 = Wt[(64 + kb) * 1024 + 768 + j];
#pragma unroll
            for (int i = 0; i < BI; ++i) {
                float4 h4 = ((const float4*)hs)[i * 64 + kb];
                a0[i] += w0.x * h4.x + w0.y * h4.y + w0.z * h4.z + w0.w * h4.w;
                a1[i] += w1.x * h4.x + w1.y * h4.y + w1.z * h4.z + w1.w * h4.w;
                a2[i] += w2.x * h4.x + w2.y * h4.y + w2.z * h4.z + w2.w * h4.w;
                a3[i] += w3.x * h4.x + w3.y * h4.y + w3.z * h4.z + w3.w * h4.w;
            }
        }
        __syncthreads();   // all dots done before any h/c write

#pragma unroll
        for (int i = 0; i < BI; ++i) {
            if (t < len[i]) {
                float gi = sigmoidf_(a0[i] + b0);
                float gf = sigmoidf_(a1[i] + b1);
                float gg = tanhf_   (a2[i] + b2);
                float go = sigmoidf_(a3[i] + b3);
                float c2 = gf * cs[i][j] + gi * gg;
                cs[i][j] = c2;
                hs[i][j] = go * tanhf_(c2);
            }
        }
        // next iteration's staging barrier orders these writes vs. reads
    }
#pragma unroll
    for (int i = 0; i < BI; ++i)
        embeds[(size_t)(n0 + i) * H_ + j] = hs[i][j];
}

// --------------------- phase 2a: XI = embeds @ Wih_i^T + b ------------------
__global__ __launch_bounds__(256, 4) void k_xi(
    const float* __restrict__ embeds, const float4* __restrict__ WiT, // [64][1024]
    const float* __restrict__ bih, const float* __restrict__ bhh,
    float* __restrict__ XI)          // [N_][1024]
{
    __shared__ __align__(16) float xs[BI][H_];
    const int j = threadIdx.x;
    const int n0 = blockIdx.x * BI;
#pragma unroll
    for (int q = 0; q < 4; ++q) {
        int idx = j + q * 256;
        int i = idx >> 6, e4 = idx & 63;
        ((float4*)xs)[i * 64 + e4] = ((const float4*)embeds)[(size_t)(n0 + i) * 64 + e4];
    }
    const float b0 = bih[j]       + bhh[j];
    const float b1 = bih[256 + j] + bhh[256 + j];
    const float b2 = bih[512 + j] + bhh[512 + j];
    const float b3 = bih[768 + j] + bhh[768 + j];
    __syncthreads();

    float a0[BI], a1[BI], a2[BI], a3[BI];
#pragma unroll
    for (int i = 0; i < BI; ++i) { a0[i] = 0.f; a1[i] = 0.f; a2[i] = 0.f; a3[i] = 0.f; }

    for (int kb = 0; kb < 64; ++kb) {
        float4 w0 = WiT[kb * 1024 + j];
        float4 w1 = WiT[kb * 1024 + 256 + j];
        float4 w2 = WiT[kb * 1024 + 512 + j];
        float4 w3 = WiT[kb * 1024 + 768 + j];
#pragma unroll
        for (int i = 0; i < BI; ++i) {
            float4 x4 = ((const float4*)xs)[i * 64 + kb];
            a0[i] += w0.x * x4.x + w0.y * x4.y + w0.z * x4.z + w0.w * x4.w;
            a1[i] += w1.x * x4.x + w1.y * x4.y + w1.z * x4.z + w1.w * x4.w;
            a2[i] += w2.x * x4.x + w2.y * x4.y + w2.z * x4.z + w2.w * x4.w;
            a3[i] += w3.x * x4.x + w3.y * x4.y + w3.z * x4.z + w3.w * x4.w;
        }
    }
#pragma unroll
    for (int i = 0; i < BI; ++i) {
        size_t base = (size_t)(n0 + i) * 1024;
        XI[base + j]       = a0[i] + b0;
        XI[base + 256 + j] = a1[i] + b1;
        XI[base + 512 + j] = a2[i] + b2;
        XI[base + 768 + j] = a3[i] + b3;
    }
}

// ----------------- phase 2b: sequential instruction LSTM -------------------
// Single workgroup, 512 threads. Thread j owns gate rows j and j+512.
// Row weights: k 0..191 as 96 half2 in VGPRs, k 192..255 in LDS (transposed,
// conflict-free b64). h kept as f16 in LDS (broadcast reads), fp32 accum.
constexpr int SMEM_SEQ = 512 /*hh*/ + 1024 /*c*/ + 4096 /*gates*/ + 16 * 1024 * 8 /*wt2*/;

__global__ __launch_bounds__(512, 2) void k_seq_lstm(
    const float* __restrict__ XI,    // [N_][1024]
    const float* __restrict__ Whh,   // [1024][256]
    float* __restrict__ outs)        // [N_][H_]
{
    extern __shared__ char smem[];
    half2_t* hh   = (half2_t*)smem;              // 128 half2 = h as f16
    float*   cbuf = (float*)(smem + 512);        // 256 f32
    float*   gates= (float*)(smem + 1536);       // 1024 f32, indexed by row
    uint2*   wt2  = (uint2*)(smem + 5632);       // [16][1024] (k-tail, 2 half2 each)

    const int j = threadIdx.x;
    const int r0 = j, r1 = j + 512;

    half2_t wa[96], wb[96];
    {
        const float4* w0v = (const float4*)(Whh + (size_t)r0 * H_);
        const float4* w1v = (const float4*)(Whh + (size_t)r1 * H_);
#pragma unroll
        for (int kq = 0; kq < 48; ++kq) {
            float4 v0 = w0v[kq], v1 = w1v[kq];
            wa[2 * kq]     = half2_t{(half_t)v0.x, (half_t)v0.y};
            wa[2 * kq + 1] = half2_t{(half_t)v0.z, (half_t)v0.w};
            wb[2 * kq]     = half2_t{(half_t)v1.x, (half_t)v1.y};
            wb[2 * kq + 1] = half2_t{(half_t)v1.z, (half_t)v1.w};
        }
#pragma unroll
        for (int q = 0; q < 16; ++q) {
            float4 v0 = w0v[48 + q], v1 = w1v[48 + q];
            uint2 u0, u1;
            u0.x = __builtin_bit_cast(unsigned, half2_t{(half_t)v0.x, (half_t)v0.y});
            u0.y = __builtin_bit_cast(unsigned, half2_t{(half_t)v0.z, (half_t)v0.w});
            u1.x = __builtin_bit_cast(unsigned, half2_t{(half_t)v1.x, (half_t)v1.y});
            u1.y = __builtin_bit_cast(unsigned, half2_t{(half_t)v1.z, (half_t)v1.w});
            wt2[q * 1024 + r0] = u0;
            wt2[q * 1024 + r1] = u1;
        }
    }
    if (j < 128) hh[j] = half2_t{(half_t)0.f, (half_t)0.f};
    if (j < 256) cbuf[j] = 0.f;
    __syncthreads();

    float xi0 = XI[r0], xi1 = XI[r1];
    for (int n = 0; n < N_; ++n) {
        float nxi0 = 0.f, nxi1 = 0.f;
        if (n + 1 < N_) {                      // prefetch next step's XI
            const float* p = XI + (size_t)(n + 1) * 1024;
            nxi0 = p[r0]; nxi1 = p[r1];
        }
        float acc0 = xi0, acc0b = 0.f, acc1 = xi1, acc1b = 0.f;
        const float4* hv = (const float4*)hh;
#pragma unroll
        for (int kk4 = 0; kk4 < 24; ++kk4) {   // k 0..191 (register weights)
            float4 h4 = hv[kk4];
            half2_t h0 = __builtin_bit_cast(half2_t, h4.x);
            half2_t h1 = __builtin_bit_cast(half2_t, h4.y);
            half2_t h2 = __builtin_bit_cast(half2_t, h4.z);
            half2_t h3 = __builtin_bit_cast(half2_t, h4.w);
            acc0  = FDOT2(wa[4 * kk4 + 0], h0, acc0);
            acc0b = FDOT2(wa[4 * kk4 + 1], h1, acc0b);
            acc0  = FDOT2(wa[4 * kk4 + 2], h2, acc0);
            acc0b = FDOT2(wa[4 * kk4 + 3], h3, acc0b);
            acc1  = FDOT2(wb[4 * kk4 + 0], h0, acc1);
            acc1b = FDOT2(wb[4 * kk4 + 1], h1, acc1b);
            acc1  = FDOT2(wb[4 * kk4 + 2], h2, acc1);
            acc1b = FDOT2(wb[4 * kk4 + 3], h3, acc1b);
        }
        const float2* hv2 = (const float2*)hh;
#pragma unroll
        for (int q = 0; q < 16; ++q) {         // k 192..255 (LDS weights)
            uint2 u0 = wt2[q * 1024 + r0];
            uint2 u1 = wt2[q * 1024 + r1];
            float2 hp = hv2[48 + q];
            half2_t hA = __builtin_bit_cast(half2_t, hp.x);
            half2_t hB = __builtin_bit_cast(half2_t, hp.y);
            acc0  = FDOT2(__builtin_bit_cast(half2_t, u0.x), hA, acc0);
            acc0b = FDOT2(__builtin_bit_cast(half2_t, u0.y), hB, acc0b);
            acc1  = FDOT2(__builtin_bit_cast(half2_t, u1.x), hA, acc1);
            acc1b = FDOT2(__builtin_bit_cast(half2_t, u1.y), hB, acc1b);
        }
        gates[r0] = acc0 + acc0b;
        gates[r1] = acc1 + acc1b;
        __syncthreads();

        if (j < 256) {
            float gi = sigmoidf_(gates[j]);
            float gf = sigmoidf_(gates[256 + j]);
            float gg = tanhf_   (gates[512 + j]);
            float go = sigmoidf_(gates[768 + j]);
            float c2 = gf * cbuf[j] + gi * gg;
            cbuf[j] = c2;
            float h2n = go * tanhf_(c2);
            ((half_t*)hh)[j] = (half_t)h2n;
            outs[(size_t)n * H_ + j] = h2n;
        }
        __syncthreads();
        xi0 = nxi0; xi1 = nxi1;
    }
}

// ------------------------- final linear head -------------------------------
// Output dtype: float32 (reference returns float32; harness reads float*).
__global__ __launch_bounds__(256) void k_final(
    const float* __restrict__ outs, const float* __restrict__ Wl,
    const float* __restrict__ bl, float* __restrict__ y)
{
    const int lane = threadIdx.x & 63;
    const int g = threadIdx.x >> 6;
    const int n = blockIdx.x * 4 + g;
    const float* row = outs + (size_t)n * H_;
    float s = row[lane] * Wl[lane] + row[64 + lane] * Wl[64 + lane]
            + row[128 + lane] * Wl[128 + lane] + row[192 + lane] * Wl[192 + lane];
#pragma unroll
    for (int off = 32; off > 0; off >>= 1) s += __shfl_down(s, off, 64);
    if (lane == 0) y[n] = s + bl[0];
}

// ---------------------------------------------------------------------------
extern "C" void kernel_launch(void* const* d_in, const int* in_sizes, int n_in,
                              void* d_out, int out_size, void* d_ws, size_t ws_size,
                              hipStream_t stream)
{
    const float* tokens = (const float*)d_in[0];
    const int*   lengths= (const int*)  d_in[1];
    const float* Wih_t  = (const float*)d_in[2];
    const float* Whh_t  = (const float*)d_in[3];
    const float* bih_t  = (const float*)d_in[4];
    const float* bhh_t  = (const float*)d_in[5];
    const float* Wih_i  = (const float*)d_in[6];
    const float* Whh_i  = (const float*)d_in[7];
    const float* bih_i  = (const float*)d_in[8];
    const float* bhh_i  = (const float*)d_in[9];
    const float* Wl     = (const float*)d_in[10];
    const float* bl     = (const float*)d_in[11];
    float* out = (float*)d_out;

    char* ws = (char*)d_ws;
    float*  embeds = (float*) (ws);                                // 8 MB
    float*  XI     = (float*) (ws + (size_t)8  * 1024 * 1024);     // 32 MB
    float*  outs   = (float*) (ws + (size_t)40 * 1024 * 1024);     // 8 MB
    float4* WcatT  = (float4*)(ws + (size_t)48 * 1024 * 1024);     // 2 MB
    float4* WiT    = (float4*)(ws + (size_t)50 * 1024 * 1024);     // 1 MB

    (void)hipFuncSetAttribute((const void*)k_seq_lstm,
        hipFuncAttributeMaxDynamicSharedMemorySize, SMEM_SEQ);

    k_transpose_cat<<<512,  256, 0, stream>>>(Wih_t, Whh_t, WcatT);
    k_transpose_i  <<<256,  256, 0, stream>>>(Wih_i, WiT);
    k_token_lstm   <<<512,  256, 0, stream>>>(tokens, lengths, WcatT, bih_t, bhh_t, embeds);
    k_xi           <<<512,  256, 0, stream>>>(embeds, WiT, bih_i, bhh_i, XI);
    k_seq_lstm     <<<1,    512, SMEM_SEQ, stream>>>(XI, Whh_i, outs);
    k_final        <<<2048, 256, 0, stream>>>(outs, Wl, bl, out);
}

// Round 3
// 17218.605 us; speedup vs baseline: 1.0163x; 1.0163x over previous
//
#include <hip/hip_runtime.h>
#include <hip/hip_bf16.h>
#include <hip/hip_fp16.h>

// ---------------------------------------------------------------------------
// ModelInstructionAggregate: token-LSTM (batch 8192, T<=16) -> sequential
// instruction-LSTM (8192 steps, batch 1) -> Linear(256->1).
// Round 3: k_seq_lstm only —
//   (a) amdgpu_waves_per_eu(2,2): round-2 compiler targeted 4 waves/EU
//       (VGPR_Count=128) and put the 192 weight-half2 in AGPRs -> one
//       v_accvgpr_read per fdot2 (~+2000 wave-instr/step, measured via
//       VALUBusy 62% * 4040cyc = 4960 instrs vs ~2900 hand-count).
//   (b) weight tail repacked for ds_read_b128 (16 reads/thread vs 32 b64).
// ---------------------------------------------------------------------------

constexpr int H_ = 256;    // hidden
constexpr int T_ = 16;     // max token steps
constexpr int N_ = 8192;   // instructions
constexpr int BI = 16;     // instructions per block in batched kernels

typedef _Float16 half_t;
typedef half_t half2_t __attribute__((ext_vector_type(2)));

#if __has_builtin(__builtin_amdgcn_fdot2)
#define FDOT2(w, h, acc) __builtin_amdgcn_fdot2((w), (h), (acc), false)
#else
__device__ __forceinline__ float fdot2_emul(half2_t w, half2_t h, float acc) {
    return acc + (float)w.x * (float)h.x + (float)w.y * (float)h.y;
}
#define FDOT2(w, h, acc) fdot2_emul((w), (h), (acc))
#endif

__device__ __forceinline__ float sigmoidf_(float x) {
    return 1.0f / (1.0f + __expf(-x));
}
__device__ __forceinline__ float tanhf_(float x) {
    return 2.0f / (1.0f + __expf(-2.0f * x)) - 1.0f;
}

// --------------------------- weight transposes -----------------------------
__global__ __launch_bounds__(256) void k_transpose_cat(
    const float* __restrict__ Wih, const float* __restrict__ Whh,
    float4* __restrict__ Wt)
{
    int tid = blockIdx.x * 256 + threadIdx.x;      // 1024 rows * 128 kb
    int kb = tid & 127, row = tid >> 7;
    float4 v = (kb < 64) ? ((const float4*)Wih)[row * 64 + kb]
                         : ((const float4*)Whh)[row * 64 + (kb - 64)];
    Wt[kb * 1024 + row] = v;
}

__global__ __launch_bounds__(256) void k_transpose_i(
    const float* __restrict__ Wsrc, float4* __restrict__ Wt)
{
    int tid = blockIdx.x * 256 + threadIdx.x;      // 1024 rows * 64 kb
    int kb = tid & 63, row = tid >> 6;
    Wt[kb * 1024 + row] = ((const float4*)Wsrc)[row * 64 + kb];
}

// ----------------------- phase 1: batched token LSTM -----------------------
__global__ __launch_bounds__(256, 4) void k_token_lstm(
    const float* __restrict__ tokens, const int* __restrict__ lengths,
    const float4* __restrict__ Wt,   // [128][1024] float4 (x-part then h-part)
    const float* __restrict__ bih, const float* __restrict__ bhh,
    float* __restrict__ embeds)      // [N_][H_]
{
    __shared__ __align__(16) float xs[BI][H_];
    __shared__ __align__(16) float hs[BI][H_];
    __shared__ __align__(16) float cs[BI][H_];
    __shared__ int len[BI];

    const int j = threadIdx.x;
    const int n0 = blockIdx.x * BI;
    if (j < BI) len[j] = lengths[n0 + j];
#pragma unroll
    for (int i = 0; i < BI; ++i) { hs[i][j] = 0.f; cs[i][j] = 0.f; }
    const float b0 = bih[j]       + bhh[j];
    const float b1 = bih[256 + j] + bhh[256 + j];
    const float b2 = bih[512 + j] + bhh[512 + j];
    const float b3 = bih[768 + j] + bhh[768 + j];
    __syncthreads();

    for (int t = 0; t < T_; ++t) {
#pragma unroll
        for (int q = 0; q < 4; ++q) {
            int idx = j + q * 256;
            int i = idx >> 6, e4 = idx & 63;
            ((float4*)xs)[i * 64 + e4] =
                ((const float4*)tokens)[((size_t)(n0 + i) * T_ + t) * 64 + e4];
        }
        __syncthreads();

        float a0[BI], a1[BI], a2[BI], a3[BI];
#pragma unroll
        for (int i = 0; i < BI; ++i) { a0[i] = 0.f; a1[i] = 0.f; a2[i] = 0.f; a3[i] = 0.f; }

        for (int kb = 0; kb < 64; ++kb) {
            float4 w0 = Wt[kb * 1024 + j];
            float4 w1 = Wt[kb * 1024 + 256 + j];
            float4 w2 = Wt[kb * 1024 + 512 + j];
            float4 w3 = Wt[kb * 1024 + 768 + j];
#pragma unroll
            for (int i = 0; i < BI; ++i) {
                float4 x4 = ((const float4*)xs)[i * 64 + kb];
                a0[i] += w0.x * x4.x + w0.y * x4.y + w0.z * x4.z + w0.w * x4.w;
                a1[i] += w1.x * x4.x + w1.y * x4.y + w1.z * x4.z + w1.w * x4.w;
                a2[i] += w2.x * x4.x + w2.y * x4.y + w2.z * x4.z + w2.w * x4.w;
                a3[i] += w3.x * x4.x + w3.y * x4.y + w3.z * x4.z + w3.w * x4.w;
            }
        }
        for (int kb = 0; kb < 64; ++kb) {
            float4 w0 = Wt[(64 + kb) * 1024 + j];
            float4 w1 = Wt[(64 + kb) * 1024 + 256 + j];
            float4 w2 = Wt[(64 + kb) * 1024 + 512 + j];
            float4 w3 = Wt[(64 + kb) * 1024 + 768 + j];
#pragma unroll
            for (int i = 0; i < BI; ++i) {
                float4 h4 = ((const float4*)hs)[i * 64 + kb];
                a0[i] += w0.x * h4.x + w0.y * h4.y + w0.z * h4.z + w0.w * h4.w;
                a1[i] += w1.x * h4.x + w1.y * h4.y + w1.z * h4.z + w1.w * h4.w;
                a2[i] += w2.x * h4.x + w2.y * h4.y + w2.z * h4.z + w2.w * h4.w;
                a3[i] += w3.x * h4.x + w3.y * h4.y + w3.z * h4.z + w3.w * h4.w;
            }
        }
        __syncthreads();

#pragma unroll
        for (int i = 0; i < BI; ++i) {
            if (t < len[i]) {
                float gi = sigmoidf_(a0[i] + b0);
                float gf = sigmoidf_(a1[i] + b1);
                float gg = tanhf_   (a2[i] + b2);
                float go = sigmoidf_(a3[i] + b3);
                float c2 = gf * cs[i][j] + gi * gg;
                cs[i][j] = c2;
                hs[i][j] = go * tanhf_(c2);
            }
        }
    }
#pragma unroll
    for (int i = 0; i < BI; ++i)
        embeds[(size_t)(n0 + i) * H_ + j] = hs[i][j];
}

// --------------------- phase 2a: XI = embeds @ Wih_i^T + b ------------------
__global__ __launch_bounds__(256, 4) void k_xi(
    const float* __restrict__ embeds, const float4* __restrict__ WiT, // [64][1024]
    const float* __restrict__ bih, const float* __restrict__ bhh,
    float* __restrict__ XI)          // [N_][1024]
{
    __shared__ __align__(16) float xs[BI][H_];
    const int j = threadIdx.x;
    const int n0 = blockIdx.x * BI;
#pragma unroll
    for (int q = 0; q < 4; ++q) {
        int idx = j + q * 256;
        int i = idx >> 6, e4 = idx & 63;
        ((float4*)xs)[i * 64 + e4] = ((const float4*)embeds)[(size_t)(n0 + i) * 64 + e4];
    }
    const float b0 = bih[j]       + bhh[j];
    const float b1 = bih[256 + j] + bhh[256 + j];
    const float b2 = bih[512 + j] + bhh[512 + j];
    const float b3 = bih[768 + j] + bhh[768 + j];
    __syncthreads();

    float a0[BI], a1[BI], a2[BI], a3[BI];
#pragma unroll
    for (int i = 0; i < BI; ++i) { a0[i] = 0.f; a1[i] = 0.f; a2[i] = 0.f; a3[i] = 0.f; }

    for (int kb = 0; kb < 64; ++kb) {
        float4 w0 = WiT[kb * 1024 + j];
        float4 w1 = WiT[kb * 1024 + 256 + j];
        float4 w2 = WiT[kb * 1024 + 512 + j];
        float4 w3 = WiT[kb * 1024 + 768 + j];
#pragma unroll
        for (int i = 0; i < BI; ++i) {
            float4 x4 = ((const float4*)xs)[i * 64 + kb];
            a0[i] += w0.x * x4.x + w0.y * x4.y + w0.z * x4.z + w0.w * x4.w;
            a1[i] += w1.x * x4.x + w1.y * x4.y + w1.z * x4.z + w1.w * x4.w;
            a2[i] += w2.x * x4.x + w2.y * x4.y + w2.z * x4.z + w2.w * x4.w;
            a3[i] += w3.x * x4.x + w3.y * x4.y + w3.z * x4.z + w3.w * x4.w;
        }
    }
#pragma unroll
    for (int i = 0; i < BI; ++i) {
        size_t base = (size_t)(n0 + i) * 1024;
        XI[base + j]       = a0[i] + b0;
        XI[base + 256 + j] = a1[i] + b1;
        XI[base + 512 + j] = a2[i] + b2;
        XI[base + 768 + j] = a3[i] + b3;
    }
}

// ----------------- phase 2b: sequential instruction LSTM -------------------
// Single workgroup, 512 threads, 2 gate rows each (r0=j, r1=j+512).
// k 0..191 in VGPRs (96 half2 per row; waves_per_eu(2,2) => 256-reg budget),
// k 192..255 in LDS packed as uint4 (8 b128 reads per row per step).
// h kept f16 in LDS, read as wave-uniform float4 broadcasts; fp32 accum.
constexpr int SMEM_SEQ = 512 /*hh*/ + 1024 /*c*/ + 4096 /*gates*/
                       + 8 * 1024 * 16 /*wt4*/;   // 136704 B total

__global__ __launch_bounds__(512)
__attribute__((amdgpu_waves_per_eu(2, 2)))
void k_seq_lstm(
    const float* __restrict__ XI,    // [N_][1024]
    const float* __restrict__ Whh,   // [1024][256]
    float* __restrict__ outs)        // [N_][H_]
{
    extern __shared__ char smem[];
    half2_t* hh   = (half2_t*)smem;              // 128 half2 = h as f16
    float*   cbuf = (float*)(smem + 512);        // 256 f32
    float*   gates= (float*)(smem + 1536);       // 1024 f32, indexed by row
    uint4*   wt4  = (uint4*)(smem + 5632);       // [8][1024] k-tail, 4 half2 each

    const int j = threadIdx.x;
    const int r0 = j, r1 = j + 512;

    half2_t wa[96], wb[96];
    {
        const float4* w0v = (const float4*)(Whh + (size_t)r0 * H_);
        const float4* w1v = (const float4*)(Whh + (size_t)r1 * H_);
#pragma unroll
        for (int kq = 0; kq < 48; ++kq) {        // k 0..191 -> regs
            float4 v0 = w0v[kq], v1 = w1v[kq];
            wa[2 * kq]     = half2_t{(half_t)v0.x, (half_t)v0.y};
            wa[2 * kq + 1] = half2_t{(half_t)v0.z, (half_t)v0.w};
            wb[2 * kq]     = half2_t{(half_t)v1.x, (half_t)v1.y};
            wb[2 * kq + 1] = half2_t{(half_t)v1.z, (half_t)v1.w};
        }
#pragma unroll
        for (int q = 0; q < 8; ++q) {            // k 192..255 -> LDS uint4
            float4 vA = w0v[48 + 2 * q], vB = w0v[48 + 2 * q + 1];
            uint4 u0;
            u0.x = __builtin_bit_cast(unsigned, half2_t{(half_t)vA.x, (half_t)vA.y});
            u0.y = __builtin_bit_cast(unsigned, half2_t{(half_t)vA.z, (half_t)vA.w});
            u0.z = __builtin_bit_cast(unsigned, half2_t{(half_t)vB.x, (half_t)vB.y});
            u0.w = __builtin_bit_cast(unsigned, half2_t{(half_t)vB.z, (half_t)vB.w});
            wt4[q * 1024 + r0] = u0;
            float4 vC = w1v[48 + 2 * q], vD = w1v[48 + 2 * q + 1];
            uint4 u1;
            u1.x = __builtin_bit_cast(unsigned, half2_t{(half_t)vC.x, (half_t)vC.y});
            u1.y = __builtin_bit_cast(unsigned, half2_t{(half_t)vC.z, (half_t)vC.w});
            u1.z = __builtin_bit_cast(unsigned, half2_t{(half_t)vD.x, (half_t)vD.y});
            u1.w = __builtin_bit_cast(unsigned, half2_t{(half_t)vD.z, (half_t)vD.w});
            wt4[q * 1024 + r1] = u1;
        }
    }
    if (j < 128) hh[j] = half2_t{(half_t)0.f, (half_t)0.f};
    if (j < 256) cbuf[j] = 0.f;
    __syncthreads();

    float xi0 = XI[r0], xi1 = XI[r1];
    for (int n = 0; n < N_; ++n) {
        float nxi0 = 0.f, nxi1 = 0.f;
        if (n + 1 < N_) {                      // prefetch next step's XI
            const float* p = XI + (size_t)(n + 1) * 1024;
            nxi0 = p[r0]; nxi1 = p[r1];
        }
        float acc0 = xi0, acc0b = 0.f, acc1 = xi1, acc1b = 0.f;
        const float4* hv = (const float4*)hh;  // wave-uniform -> LDS broadcast
#pragma unroll
        for (int kk4 = 0; kk4 < 24; ++kk4) {   // k 0..191 (register weights)
            float4 h4 = hv[kk4];
            half2_t h0 = __builtin_bit_cast(half2_t, h4.x);
            half2_t h1 = __builtin_bit_cast(half2_t, h4.y);
            half2_t h2 = __builtin_bit_cast(half2_t, h4.z);
            half2_t h3 = __builtin_bit_cast(half2_t, h4.w);
            acc0  = FDOT2(wa[4 * kk4 + 0], h0, acc0);
            acc0b = FDOT2(wa[4 * kk4 + 1], h1, acc0b);
            acc0  = FDOT2(wa[4 * kk4 + 2], h2, acc0);
            acc0b = FDOT2(wa[4 * kk4 + 3], h3, acc0b);
            acc1  = FDOT2(wb[4 * kk4 + 0], h0, acc1);
            acc1b = FDOT2(wb[4 * kk4 + 1], h1, acc1b);
            acc1  = FDOT2(wb[4 * kk4 + 2], h2, acc1);
            acc1b = FDOT2(wb[4 * kk4 + 3], h3, acc1b);
        }
#pragma unroll
        for (int q = 0; q < 8; ++q) {          // k 192..255 (LDS weights, b128)
            uint4 u0 = wt4[q * 1024 + r0];
            uint4 u1 = wt4[q * 1024 + r1];
            float4 h4 = hv[24 + q];
            half2_t h0 = __builtin_bit_cast(half2_t, h4.x);
            half2_t h1 = __builtin_bit_cast(half2_t, h4.y);
            half2_t h2 = __builtin_bit_cast(half2_t, h4.z);
            half2_t h3 = __builtin_bit_cast(half2_t, h4.w);
            acc0  = FDOT2(__builtin_bit_cast(half2_t, u0.x), h0, acc0);
            acc0b = FDOT2(__builtin_bit_cast(half2_t, u0.y), h1, acc0b);
            acc0  = FDOT2(__builtin_bit_cast(half2_t, u0.z), h2, acc0);
            acc0b = FDOT2(__builtin_bit_cast(half2_t, u0.w), h3, acc0b);
            acc1  = FDOT2(__builtin_bit_cast(half2_t, u1.x), h0, acc1);
            acc1b = FDOT2(__builtin_bit_cast(half2_t, u1.y), h1, acc1b);
            acc1  = FDOT2(__builtin_bit_cast(half2_t, u1.z), h2, acc1);
            acc1b = FDOT2(__builtin_bit_cast(half2_t, u1.w), h3, acc1b);
        }
        gates[r0] = acc0 + acc0b;
        gates[r1] = acc1 + acc1b;
        __syncthreads();

        if (j < 256) {
            float gi = sigmoidf_(gates[j]);
            float gf = sigmoidf_(gates[256 + j]);
            float gg = tanhf_   (gates[512 + j]);
            float go = sigmoidf_(gates[768 + j]);
            float c2 = gf * cbuf[j] + gi * gg;
            cbuf[j] = c2;
            float h2n = go * tanhf_(c2);
            ((half_t*)hh)[j] = (half_t)h2n;
            outs[(size_t)n * H_ + j] = h2n;
        }
        __syncthreads();
        xi0 = nxi0; xi1 = nxi1;
    }
}

// ------------------------- final linear head -------------------------------
__global__ __launch_bounds__(256) void k_final(
    const float* __restrict__ outs, const float* __restrict__ Wl,
    const float* __restrict__ bl, float* __restrict__ y)
{
    const int lane = threadIdx.x & 63;
    const int g = threadIdx.x >> 6;
    const int n = blockIdx.x * 4 + g;
    const float* row = outs + (size_t)n * H_;
    float s = row[lane] * Wl[lane] + row[64 + lane] * Wl[64 + lane]
            + row[128 + lane] * Wl[128 + lane] + row[192 + lane] * Wl[192 + lane];
#pragma unroll
    for (int off = 32; off > 0; off >>= 1) s += __shfl_down(s, off, 64);
    if (lane == 0) y[n] = s + bl[0];
}

// ---------------------------------------------------------------------------
extern "C" void kernel_launch(void* const* d_in, const int* in_sizes, int n_in,
                              void* d_out, int out_size, void* d_ws, size_t ws_size,
                              hipStream_t stream)
{
    const float* tokens = (const float*)d_in[0];
    const int*   lengths= (const int*)  d_in[1];
    const float* Wih_t  = (const float*)d_in[2];
    const float* Whh_t  = (const float*)d_in[3];
    const float* bih_t  = (const float*)d_in[4];
    const float* bhh_t  = (const float*)d_in[5];
    const float* Wih_i  = (const float*)d_in[6];
    const float* Whh_i  = (const float*)d_in[7];
    const float* bih_i  = (const float*)d_in[8];
    const float* bhh_i  = (const float*)d_in[9];
    const float* Wl     = (const float*)d_in[10];
    const float* bl     = (const float*)d_in[11];
    float* out = (float*)d_out;

    char* ws = (char*)d_ws;
    float*  embeds = (float*) (ws);                                // 8 MB
    float*  XI     = (float*) (ws + (size_t)8  * 1024 * 1024);     // 32 MB
    float*  outs   = (float*) (ws + (size_t)40 * 1024 * 1024);     // 8 MB
    float4* WcatT  = (float4*)(ws + (size_t)48 * 1024 * 1024);     // 2 MB
    float4* WiT    = (float4*)(ws + (size_t)50 * 1024 * 1024);     // 1 MB

    (void)hipFuncSetAttribute((const void*)k_seq_lstm,
        hipFuncAttributeMaxDynamicSharedMemorySize, SMEM_SEQ);

    k_transpose_cat<<<512,  256, 0, stream>>>(Wih_t, Whh_t, WcatT);
    k_transpose_i  <<<256,  256, 0, stream>>>(Wih_i, WiT);
    k_token_lstm   <<<512,  256, 0, stream>>>(tokens, lengths, WcatT, bih_t, bhh_t, embeds);
    k_xi           <<<512,  256, 0, stream>>>(embeds, WiT, bih_i, bhh_i, XI);
    k_seq_lstm     <<<1,    512, SMEM_SEQ, stream>>>(XI, Whh_i, outs);
    k_final        <<<2048, 256, 0, stream>>>(outs, Wl, bl, out);
}